// Round 9
// baseline (401.805 us; speedup 1.0000x reference)
//
#include <hip/hip_runtime.h>
#include <math.h>

// Problem constants
#define KC 1024       // num codes
#define DD 256        // embedding dim
#define NROWS 32768   // 32 * 32 * 32 (B*H*W)
#define NELEM 8388608 // NROWS * DD

typedef _Float16 f16;
typedef __attribute__((ext_vector_type(8))) _Float16 f16x8;
typedef __attribute__((ext_vector_type(16))) float f32x16;

#define KEY_SCALE 2097152.0f   // 2^21; |score| <= ~0.63 -> |ikey| < 2^21
#define KEY_INV   (1.0f / 2097152.0f)

// ---------------------------------------------------------------------------
// prep: c_sq (exact fp32) + emb -> fp16 swizzled. Nothing to zero (the
// pipeline has NO global accumulators). grid 256 x 256.
// emb_h layout: [kg 32][code 1024][8]
// ---------------------------------------------------------------------------
__global__ void vq_prep_kernel(const float* __restrict__ emb, f16* __restrict__ emb_h,
                               float* __restrict__ c_sq) {
    const int tid = threadIdx.x;
    const int gt = blockIdx.x * 256 + tid;
    {
        int k = blockIdx.x * 4 + (tid >> 6);
        int lane = tid & 63;
        float4 v = *(const float4*)(emb + (size_t)k * DD + lane * 4);
        float s = v.x * v.x + v.y * v.y + v.z * v.z + v.w * v.w;
        #pragma unroll
        for (int off = 32; off > 0; off >>= 1) s += __shfl_down(s, off);
        if (lane == 0) c_sq[k] = s;
    }
    if (gt < 32768) {
        int code = gt & 1023;
        int kg = gt >> 10;
        const float* p = emb + (size_t)code * DD + kg * 8;
        float4 v0 = *(const float4*)p;
        float4 v1 = *(const float4*)(p + 4);
        f16x8 hcv;
        hcv[0] = (f16)v0.x; hcv[1] = (f16)v0.y; hcv[2] = (f16)v0.z; hcv[3] = (f16)v0.w;
        hcv[4] = (f16)v1.x; hcv[5] = (f16)v1.y; hcv[6] = (f16)v1.z; hcv[7] = (f16)v1.w;
        *(f16x8*)(emb_h + (size_t)gt * 8) = hcv;
    }
}

// ---------------------------------------------------------------------------
// K1: argmin producer, swapped-operand MFMA, zero global atomics, now with a
// 2-DEEP SOFTWARE PIPELINE on the emb fragment loads:
//   each ks iteration's ea load (L2, ~200-400cy) was serially feeding 2 MFMAs
//   (~64cy own-wave issue) -> per-iteration vmcnt stall at 4 waves/SIMD.
//   Rotation eaA/eaB issues ea(ks+2) while computing ks; the next chunk's
//   first two loads are issued BEFORE the argmin epilogue (~80 VALU ops)
//   so chunk boundaries don't stall either.
// c_sq is staged once into LDS (csq_s, 4KB) in Phase A -> epilogue reads are
// LDS broadcasts instead of 64 per-wave L2 loads per block.
// grid 512, 512 threads (8 waves), 64 rows/block, ALL 1024 codes/block.
//   mfma(emb_frag, z_frag): D[code][zrow] -> lane = z row, reg = code;
//   argmin over codes in-register + one shfl_xor(32) half-merge.
// Outputs: idx_g (plain stores), loss_blk[bid] (plain store).
// FP math order identical to R8 -> bit-identical keys/idx/absmax.
// ---------------------------------------------------------------------------
__global__ __launch_bounds__(512, 4)
void vq_argmin_kernel(const float* __restrict__ z, const f16* __restrict__ emb_h,
                      const float* __restrict__ c_sq, int* __restrict__ idx_g,
                      float* __restrict__ loss_blk) {
    __shared__ __align__(16) f16 z_s[32 * 64 * 8];   // [kg 32][row 64][8] = 32768 B
    __shared__ int   bl_key[8][64];                   // 2048 B
    __shared__ float zsq_part[8][64];                 // 2048 B
    __shared__ float csq_s[KC];                       // 4096 B

    const int tid = threadIdx.x;
    const int n0 = blockIdx.x * 64;
    const int b = n0 >> 10;
    const int hw0 = n0 & 1023;

    // ---- Phase A: stage z tile fp16 + ||z||^2 partials + c_sq -> LDS ----
    csq_s[tid] = c_sq[tid];
    csq_s[tid + 512] = c_sq[tid + 512];
    {
        const int r = tid & 63;
        const int kq = tid >> 6;  // 0..7
        const float* zp = z + (size_t)b * (DD * 1024) + hw0 + r;
        float sq = 0.f;
        #pragma unroll
        for (int it = 0; it < 4; ++it) {
            int kg = kq * 4 + it;
            f16x8 hv;
            #pragma unroll
            for (int j = 0; j < 8; ++j) {
                float v = zp[(size_t)(kg * 8 + j) * 1024];
                sq += v * v;
                hv[j] = (f16)v;
            }
            *(f16x8*)&z_s[(kg * 64 + r) * 8] = hv;
        }
        zsq_part[kq][r] = sq;
    }
    __syncthreads();

    const int m = tid & 31;        // lane -> z row (D col)
    const int h = (tid >> 5) & 1;  // k-half; also selects code subset (+4h)
    const int w = tid >> 6;        // wave id 0..7

    int kmin0 = 0x7FFFFFFF;        // running key, z rows m
    int kmin1 = 0x7FFFFFFF;        // running key, z rows m+32

    // ---- Phase B: wave owns 128 codes as 4 chunks of 32, pipelined ----
    const f16* ebp = emb_h + (size_t)h * 8192 + (size_t)(w * 128 + m) * 8;
    f16x8 eaA = *(const f16x8*)(ebp);                  // ks=0 in flight
    f16x8 eaB = *(const f16x8*)(ebp + 16384);          // ks=1 in flight

    for (int c = 0; c < 4; ++c) {
        const int cb = w * 128 + c * 32;               // chunk base code

        f32x16 acc0, acc1;   // D[code][row] for z rows 0-31 / 32-63
        #pragma unroll
        for (int i = 0; i < 16; ++i) { acc0[i] = 0.f; acc1[i] = 0.f; }

        #pragma unroll
        for (int ks = 0; ks < 16; ++ks) {
            f16x8 ea = eaA;
            eaA = eaB;
            if (ks < 14) eaB = *(const f16x8*)(ebp + (size_t)(ks + 2) * 16384);
            const f16* za = z_s + ((size_t)(2 * ks + h) * 64 + m) * 8;
            f16x8 zb0 = *(const f16x8*)(za);           // z rows 0-31  (B frag)
            f16x8 zb1 = *(const f16x8*)(za + 256);     // z rows 32-63 (B frag)
            acc0 = __builtin_amdgcn_mfma_f32_32x32x16_f16(ea, zb0, acc0, 0, 0, 0);
            acc1 = __builtin_amdgcn_mfma_f32_32x32x16_f16(ea, zb1, acc1, 0, 0, 0);
        }

        // issue next chunk's first two loads BEFORE the epilogue so the
        // argmin VALU work covers their latency
        const f16* ebn = ebp + 256;                    // codes +32
        if (c < 3) {
            eaA = *(const f16x8*)(ebn);
            eaB = *(const f16x8*)(ebn + 16384);
        }
        ebp = ebn;

        // in-register argmin over the 16 codes this lane holds
        #pragma unroll
        for (int reg = 0; reg < 16; ++reg) {
            int code = cb + (reg & 3) + 8 * (reg >> 2) + 4 * h;
            float cs = csq_s[code];
            float s0 = fmaf(-2.f, acc0[reg], cs);
            float s1 = fmaf(-2.f, acc1[reg], cs);
            kmin0 = min(kmin0, (int)(s0 * KEY_SCALE) * 1024 + code);
            kmin1 = min(kmin1, (int)(s1 * KEY_SCALE) * 1024 + code);
        }
    }

    // merge lane-halves (lanes m and m+32 hold the same z row, disjoint codes)
    kmin0 = min(kmin0, __shfl_xor(kmin0, 32));
    kmin1 = min(kmin1, __shfl_xor(kmin1, 32));
    if (h == 0) { bl_key[w][m] = kmin0; bl_key[w][32 + m] = kmin1; }
    __syncthreads();

    // ---- combine 8 waves -> idx store + per-block loss (plain stores) ----
    if (tid < 64) {
        int k = bl_key[0][tid];
        #pragma unroll
        for (int w2 = 1; w2 < 8; ++w2) k = min(k, bl_key[w2][tid]);
        idx_g[n0 + tid] = k & 1023;     // low 10 bits = code
        float zq = 0.f;
        #pragma unroll
        for (int p = 0; p < 8; ++p) zq += zsq_part[p][tid];
        float lr = (float)(k >> 10) * KEY_INV + zq;  // score_min + ||z||^2
        #pragma unroll
        for (int off = 32; off > 0; off >>= 1) lr += __shfl_down(lr, off);
        if (tid == 0) loss_blk[blockIdx.x] = lr;     // NO atomic
    }
}

// ---------------------------------------------------------------------------
// K2: grid 1025. Blocks 0..1023 = writers (tile x channel-half), transposed
// LDS stage Qt[128][65], full 256B out lines, zero atomics/fences. Block
// 1024 = finalize (depends only on K1 outputs; kernel-boundary coherent):
// LDS histogram of idx_g -> entropy; sum loss_blk -> loss.
// ---------------------------------------------------------------------------
__global__ __launch_bounds__(512, 4)
void vq_out_kernel(const float* __restrict__ emb, const int* __restrict__ idx_g,
                   const float* __restrict__ loss_blk, float* __restrict__ out,
                   float* __restrict__ out_tail) {
    __shared__ float Qt[128][65];   // 33280 B, transposed: [ch][row]
    __shared__ int   idx_s[64];

    const int tid = threadIdx.x;

    if (blockIdx.x == 1024) {
        // ---- finalize block ----
        __shared__ int   hist[KC];
        __shared__ float wsum[8];
        for (int k = tid; k < KC; k += 512) hist[k] = 0;
        __syncthreads();
        for (int i = tid; i < NROWS; i += 512)
            atomicAdd(&hist[idx_g[i]], 1);           // LDS atomic (cheap)
        __syncthreads();
        float s = 0.f;
        for (int k = tid; k < KC; k += 512) {
            float pr = (float)hist[k] * (1.0f / (float)NROWS);
            s += pr * logf(pr + 1e-10f);
        }
        float lv = loss_blk[tid];                    // 512 partials, 1/thread
        #pragma unroll
        for (int off = 32; off > 0; off >>= 1) {
            s  += __shfl_down(s, off);
            lv += __shfl_down(lv, off);
        }
        if ((tid & 63) == 0) { wsum[tid >> 6] = s; Qt[0][tid >> 6] = lv; }
        __syncthreads();
        if (tid == 0) {
            float ent = 0.f, loss_tot = 0.f;
            #pragma unroll
            for (int p = 0; p < 8; ++p) { ent += wsum[p]; loss_tot += Qt[0][p]; }
            out_tail[0] = 1.25f * loss_tot * (1.0f / (float)NELEM);
            out_tail[1] = expf(-ent);
        }
        return;
    }

    const int tile = blockIdx.x >> 1;
    const int ch0 = (blockIdx.x & 1) * 128;
    const int n0 = tile * 64;
    const int b = n0 >> 10;
    const int hw0 = n0 & 1023;

    if (tid < 64) idx_s[tid] = idx_g[n0 + tid];
    __syncthreads();

    // stage: thread (p=tid>>6, r=tid&63) loads emb[idx[r]][ch0+p*16..+16]
    // (coalesced 64B/lane from L2), scatters into Qt columns.
    {
        int r = tid & 63;
        int p = tid >> 6;
        const float* ep = emb + (size_t)idx_s[r] * DD + ch0 + p * 16;
        float4 v0 = *(const float4*)(ep);
        float4 v1 = *(const float4*)(ep + 4);
        float4 v2 = *(const float4*)(ep + 8);
        float4 v3 = *(const float4*)(ep + 12);
        float vv[16] = {v0.x, v0.y, v0.z, v0.w, v1.x, v1.y, v1.z, v1.w,
                        v2.x, v2.y, v2.z, v2.w, v3.x, v3.y, v3.z, v3.w};
        #pragma unroll
        for (int g = 0; g < 16; ++g)
            Qt[p * 16 + g][r] = vv[g];   // lanes r consecutive -> conflict-free
    }
    __syncthreads();

    // drain: wave w covers channels [w*16,(w+1)*16); per channel the 64 lanes
    // write one full 256B contiguous line of out. Then exit — no fence,
    // no atomic, no done counter.
    {
        int lane = tid & 63;
        int w = tid >> 6;
        const size_t base = (size_t)b * (DD * 1024) + hw0 + lane;
        #pragma unroll
        for (int g = 0; g < 16; ++g) {
            int ch = w * 16 + g;
            out[base + (size_t)(ch0 + ch) * 1024] = Qt[ch][lane];
        }
    }
}

// ---------------------------------------------------------------------------
extern "C" void kernel_launch(void* const* d_in, const int* in_sizes, int n_in,
                              void* d_out, int out_size, void* d_ws, size_t ws_size,
                              hipStream_t stream) {
    const float* z = (const float*)d_in[0];    // (32,256,32,32)
    const float* emb = (const float*)d_in[1];  // (1024,256)
    float* out = (float*)d_out;                // 8388608 + 2

    char* wsb = (char*)d_ws;
    f16* emb_h = (f16*)wsb;                        // 524288 B
    float* c_sq = (float*)(wsb + 524288);          // 4096 B
    int* idx_g = (int*)(wsb + 528384);             // 131072 B
    float* loss_blk = (float*)(wsb + 659456);      // 2048 B

    hipLaunchKernelGGL(vq_prep_kernel, dim3(256), dim3(256), 0, stream,
                       emb, emb_h, c_sq);
    hipLaunchKernelGGL(vq_argmin_kernel, dim3(512), dim3(512), 0, stream,
                       z, emb_h, c_sq, idx_g, loss_blk);
    hipLaunchKernelGGL(vq_out_kernel, dim3(1025), dim3(512), 0, stream,
                       emb, idx_g, loss_blk, out, out + NELEM);
}

// Round 10
// 177.996 us; speedup vs baseline: 2.2574x; 2.2574x over previous
//
#include <hip/hip_runtime.h>
#include <math.h>

// Problem constants
#define KC 1024       // num codes
#define DD 256        // embedding dim
#define NROWS 32768   // 32 * 32 * 32 (B*H*W)
#define NELEM 8388608 // NROWS * DD

typedef _Float16 f16;
typedef __attribute__((ext_vector_type(8))) _Float16 f16x8;
typedef __attribute__((ext_vector_type(16))) float f32x16;

#define KEY_SCALE 2097152.0f   // 2^21; |score| <= ~0.63 -> |ikey| < 2^21
#define KEY_INV   (1.0f / 2097152.0f)

// ---------------------------------------------------------------------------
// prep: c_sq (exact fp32) + emb -> fp16 swizzled. Nothing to zero (the
// pipeline has NO global accumulators). grid 256 x 256.
// emb_h layout: [kg 32][code 1024][8]
// ---------------------------------------------------------------------------
__global__ void vq_prep_kernel(const float* __restrict__ emb, f16* __restrict__ emb_h,
                               float* __restrict__ c_sq) {
    const int tid = threadIdx.x;
    const int gt = blockIdx.x * 256 + tid;
    {
        int k = blockIdx.x * 4 + (tid >> 6);
        int lane = tid & 63;
        float4 v = *(const float4*)(emb + (size_t)k * DD + lane * 4);
        float s = v.x * v.x + v.y * v.y + v.z * v.z + v.w * v.w;
        #pragma unroll
        for (int off = 32; off > 0; off >>= 1) s += __shfl_down(s, off);
        if (lane == 0) c_sq[k] = s;
    }
    if (gt < 32768) {
        int code = gt & 1023;
        int kg = gt >> 10;
        const float* p = emb + (size_t)code * DD + kg * 8;
        float4 v0 = *(const float4*)p;
        float4 v1 = *(const float4*)(p + 4);
        f16x8 hcv;
        hcv[0] = (f16)v0.x; hcv[1] = (f16)v0.y; hcv[2] = (f16)v0.z; hcv[3] = (f16)v0.w;
        hcv[4] = (f16)v1.x; hcv[5] = (f16)v1.y; hcv[6] = (f16)v1.z; hcv[7] = (f16)v1.w;
        *(f16x8*)(emb_h + (size_t)gt * 8) = hcv;
    }
}

// ---------------------------------------------------------------------------
// K1: argmin producer, swapped-operand MFMA, zero global atomics.
// EXACT R8 loop structure (plain loads, #pragma unroll 2) — the R9 manual
// 2-deep pipeline extended fragment live ranges across the unrolled MFMA
// body, pinned the allocator at 64 arch VGPRs, and spilled ~1.4GB/dispatch
// to scratch (309-375us). Lesson kept as a comment so it is not retried:
// NEVER carry rotation registers across an unrolled MFMA cluster here.
// Only R9 piece retained: csq_s LDS broadcast table (register-neutral).
// grid 512, 512 threads (8 waves), 64 rows/block, ALL 1024 codes/block.
//   mfma(emb_frag, z_frag): D[code][zrow] -> lane = z row, reg = code;
//   argmin over codes in-register + one shfl_xor(32) half-merge.
// Outputs: idx_g (plain stores), loss_blk[bid] (plain store).
// FP math order identical to R8 -> bit-identical keys/idx/absmax.
// ---------------------------------------------------------------------------
__global__ __launch_bounds__(512, 4)
void vq_argmin_kernel(const float* __restrict__ z, const f16* __restrict__ emb_h,
                      const float* __restrict__ c_sq, int* __restrict__ idx_g,
                      float* __restrict__ loss_blk) {
    __shared__ __align__(16) f16 z_s[32 * 64 * 8];   // [kg 32][row 64][8] = 32768 B
    __shared__ int   bl_key[8][64];                   // 2048 B
    __shared__ float zsq_part[8][64];                 // 2048 B
    __shared__ float csq_s[KC];                       // 4096 B

    const int tid = threadIdx.x;
    const int n0 = blockIdx.x * 64;
    const int b = n0 >> 10;
    const int hw0 = n0 & 1023;

    // ---- Phase A: stage z tile fp16 + ||z||^2 partials + c_sq -> LDS ----
    csq_s[tid] = c_sq[tid];
    csq_s[tid + 512] = c_sq[tid + 512];
    {
        const int r = tid & 63;
        const int kq = tid >> 6;  // 0..7
        const float* zp = z + (size_t)b * (DD * 1024) + hw0 + r;
        float sq = 0.f;
        #pragma unroll
        for (int it = 0; it < 4; ++it) {
            int kg = kq * 4 + it;
            f16x8 hv;
            #pragma unroll
            for (int j = 0; j < 8; ++j) {
                float v = zp[(size_t)(kg * 8 + j) * 1024];
                sq += v * v;
                hv[j] = (f16)v;
            }
            *(f16x8*)&z_s[(kg * 64 + r) * 8] = hv;
        }
        zsq_part[kq][r] = sq;
    }
    __syncthreads();

    const int m = tid & 31;        // lane -> z row (D col)
    const int h = (tid >> 5) & 1;  // k-half; also selects code subset (+4h)
    const int w = tid >> 6;        // wave id 0..7

    int kmin0 = 0x7FFFFFFF;        // running key, z rows m
    int kmin1 = 0x7FFFFFFF;        // running key, z rows m+32

    // ---- Phase B: wave owns 128 codes as 4 chunks of 32 ----
    for (int c = 0; c < 4; ++c) {
        const int cb = w * 128 + c * 32;               // chunk base code
        const f16* ebp = emb_h + (size_t)h * 8192 + (size_t)(cb + m) * 8;

        f32x16 acc0, acc1;   // D[code][row] for z rows 0-31 / 32-63
        #pragma unroll
        for (int i = 0; i < 16; ++i) { acc0[i] = 0.f; acc1[i] = 0.f; }

        #pragma unroll 2
        for (int ks = 0; ks < 16; ++ks) {
            const f16* za = z_s + ((size_t)(2 * ks + h) * 64 + m) * 8;
            f16x8 zb0 = *(const f16x8*)(za);           // z rows 0-31  (B frag)
            f16x8 zb1 = *(const f16x8*)(za + 256);     // z rows 32-63 (B frag)
            f16x8 ea  = *(const f16x8*)(ebp + (size_t)ks * 16384); // emb (A frag)
            acc0 = __builtin_amdgcn_mfma_f32_32x32x16_f16(ea, zb0, acc0, 0, 0, 0);
            acc1 = __builtin_amdgcn_mfma_f32_32x32x16_f16(ea, zb1, acc1, 0, 0, 0);
        }

        // in-register argmin over the 16 codes this lane holds
        #pragma unroll
        for (int reg = 0; reg < 16; ++reg) {
            int code = cb + (reg & 3) + 8 * (reg >> 2) + 4 * h;
            float cs = csq_s[code];
            float s0 = fmaf(-2.f, acc0[reg], cs);
            float s1 = fmaf(-2.f, acc1[reg], cs);
            kmin0 = min(kmin0, (int)(s0 * KEY_SCALE) * 1024 + code);
            kmin1 = min(kmin1, (int)(s1 * KEY_SCALE) * 1024 + code);
        }
    }

    // merge lane-halves (lanes m and m+32 hold the same z row, disjoint codes)
    kmin0 = min(kmin0, __shfl_xor(kmin0, 32));
    kmin1 = min(kmin1, __shfl_xor(kmin1, 32));
    if (h == 0) { bl_key[w][m] = kmin0; bl_key[w][32 + m] = kmin1; }
    __syncthreads();

    // ---- combine 8 waves -> idx store + per-block loss (plain stores) ----
    if (tid < 64) {
        int k = bl_key[0][tid];
        #pragma unroll
        for (int w2 = 1; w2 < 8; ++w2) k = min(k, bl_key[w2][tid]);
        idx_g[n0 + tid] = k & 1023;     // low 10 bits = code
        float zq = 0.f;
        #pragma unroll
        for (int p = 0; p < 8; ++p) zq += zsq_part[p][tid];
        float lr = (float)(k >> 10) * KEY_INV + zq;  // score_min + ||z||^2
        #pragma unroll
        for (int off = 32; off > 0; off >>= 1) lr += __shfl_down(lr, off);
        if (tid == 0) loss_blk[blockIdx.x] = lr;     // NO atomic
    }
}

// ---------------------------------------------------------------------------
// K2: grid 1025. Blocks 0..1023 = writers (tile x channel-half), transposed
// LDS stage Qt[128][65], full 256B out lines, zero atomics/fences. Block
// 1024 = finalize (depends only on K1 outputs; kernel-boundary coherent):
// LDS histogram of idx_g -> entropy; sum loss_blk -> loss.
// ---------------------------------------------------------------------------
__global__ __launch_bounds__(512, 4)
void vq_out_kernel(const float* __restrict__ emb, const int* __restrict__ idx_g,
                   const float* __restrict__ loss_blk, float* __restrict__ out,
                   float* __restrict__ out_tail) {
    __shared__ float Qt[128][65];   // 33280 B, transposed: [ch][row]
    __shared__ int   idx_s[64];

    const int tid = threadIdx.x;

    if (blockIdx.x == 1024) {
        // ---- finalize block ----
        __shared__ int   hist[KC];
        __shared__ float wsum[8];
        for (int k = tid; k < KC; k += 512) hist[k] = 0;
        __syncthreads();
        for (int i = tid; i < NROWS; i += 512)
            atomicAdd(&hist[idx_g[i]], 1);           // LDS atomic (cheap)
        __syncthreads();
        float s = 0.f;
        for (int k = tid; k < KC; k += 512) {
            float pr = (float)hist[k] * (1.0f / (float)NROWS);
            s += pr * logf(pr + 1e-10f);
        }
        float lv = loss_blk[tid];                    // 512 partials, 1/thread
        #pragma unroll
        for (int off = 32; off > 0; off >>= 1) {
            s  += __shfl_down(s, off);
            lv += __shfl_down(lv, off);
        }
        if ((tid & 63) == 0) { wsum[tid >> 6] = s; Qt[0][tid >> 6] = lv; }
        __syncthreads();
        if (tid == 0) {
            float ent = 0.f, loss_tot = 0.f;
            #pragma unroll
            for (int p = 0; p < 8; ++p) { ent += wsum[p]; loss_tot += Qt[0][p]; }
            out_tail[0] = 1.25f * loss_tot * (1.0f / (float)NELEM);
            out_tail[1] = expf(-ent);
        }
        return;
    }

    const int tile = blockIdx.x >> 1;
    const int ch0 = (blockIdx.x & 1) * 128;
    const int n0 = tile * 64;
    const int b = n0 >> 10;
    const int hw0 = n0 & 1023;

    if (tid < 64) idx_s[tid] = idx_g[n0 + tid];
    __syncthreads();

    // stage: thread (p=tid>>6, r=tid&63) loads emb[idx[r]][ch0+p*16..+16]
    // (coalesced 64B/lane from L2), scatters into Qt columns.
    {
        int r = tid & 63;
        int p = tid >> 6;
        const float* ep = emb + (size_t)idx_s[r] * DD + ch0 + p * 16;
        float4 v0 = *(const float4*)(ep);
        float4 v1 = *(const float4*)(ep + 4);
        float4 v2 = *(const float4*)(ep + 8);
        float4 v3 = *(const float4*)(ep + 12);
        float vv[16] = {v0.x, v0.y, v0.z, v0.w, v1.x, v1.y, v1.z, v1.w,
                        v2.x, v2.y, v2.z, v2.w, v3.x, v3.y, v3.z, v3.w};
        #pragma unroll
        for (int g = 0; g < 16; ++g)
            Qt[p * 16 + g][r] = vv[g];   // lanes r consecutive -> conflict-free
    }
    __syncthreads();

    // drain: wave w covers channels [w*16,(w+1)*16); per channel the 64 lanes
    // write one full 256B contiguous line of out. Then exit — no fence,
    // no atomic, no done counter.
    {
        int lane = tid & 63;
        int w = tid >> 6;
        const size_t base = (size_t)b * (DD * 1024) + hw0 + lane;
        #pragma unroll
        for (int g = 0; g < 16; ++g) {
            int ch = w * 16 + g;
            out[base + (size_t)(ch0 + ch) * 1024] = Qt[ch][lane];
        }
    }
}

// ---------------------------------------------------------------------------
extern "C" void kernel_launch(void* const* d_in, const int* in_sizes, int n_in,
                              void* d_out, int out_size, void* d_ws, size_t ws_size,
                              hipStream_t stream) {
    const float* z = (const float*)d_in[0];    // (32,256,32,32)
    const float* emb = (const float*)d_in[1];  // (1024,256)
    float* out = (float*)d_out;                // 8388608 + 2

    char* wsb = (char*)d_ws;
    f16* emb_h = (f16*)wsb;                        // 524288 B
    float* c_sq = (float*)(wsb + 524288);          // 4096 B
    int* idx_g = (int*)(wsb + 528384);             // 131072 B
    float* loss_blk = (float*)(wsb + 659456);      // 2048 B

    hipLaunchKernelGGL(vq_prep_kernel, dim3(256), dim3(256), 0, stream,
                       emb, emb_h, c_sq);
    hipLaunchKernelGGL(vq_argmin_kernel, dim3(512), dim3(512), 0, stream,
                       z, emb_h, c_sq, idx_g, loss_blk);
    hipLaunchKernelGGL(vq_out_kernel, dim3(1025), dim3(512), 0, stream,
                       emb, idx_g, loss_blk, out, out + NELEM);
}

// Round 11
// 143.916 us; speedup vs baseline: 2.7919x; 1.2368x over previous
//
#include <hip/hip_runtime.h>
#include <math.h>

// Problem constants
#define KC 1024       // num codes
#define DD 256        // embedding dim
#define NROWS 32768   // 32 * 32 * 32 (B*H*W)
#define NELEM 8388608 // NROWS * DD

typedef _Float16 f16;
typedef __attribute__((ext_vector_type(8))) _Float16 f16x8;
typedef __attribute__((ext_vector_type(16))) float f32x16;

#define KEY_SCALE 2097152.0f   // 2^21; |score| <= ~0.63 -> |ikey| < 2^21
#define KEY_INV   (1.0f / 2097152.0f)

// ---------------------------------------------------------------------------
// prep: c_sq (exact fp32) + emb -> fp16 swizzled + key_ws = INT_MAX.
// grid 256 x 256.  emb_h layout: [kg 32][code 1024][8]
// ---------------------------------------------------------------------------
__global__ void vq_prep_kernel(const float* __restrict__ emb, f16* __restrict__ emb_h,
                               float* __restrict__ c_sq, int* __restrict__ key_ws) {
    const int tid = threadIdx.x;
    const int gt = blockIdx.x * 256 + tid;
    if (gt < 32768) key_ws[gt] = 0x7FFFFFFF;
    {
        int k = blockIdx.x * 4 + (tid >> 6);
        int lane = tid & 63;
        float4 v = *(const float4*)(emb + (size_t)k * DD + lane * 4);
        float s = v.x * v.x + v.y * v.y + v.z * v.z + v.w * v.w;
        #pragma unroll
        for (int off = 32; off > 0; off >>= 1) s += __shfl_down(s, off);
        if (lane == 0) c_sq[k] = s;
    }
    if (gt < 32768) {
        int code = gt & 1023;
        int kg = gt >> 10;
        const float* p = emb + (size_t)code * DD + kg * 8;
        float4 v0 = *(const float4*)p;
        float4 v1 = *(const float4*)(p + 4);
        f16x8 hcv;
        hcv[0] = (f16)v0.x; hcv[1] = (f16)v0.y; hcv[2] = (f16)v0.z; hcv[3] = (f16)v0.w;
        hcv[4] = (f16)v1.x; hcv[5] = (f16)v1.y; hcv[6] = (f16)v1.z; hcv[7] = (f16)v1.w;
        *(f16x8*)(emb_h + (size_t)gt * 8) = hcv;
    }
}

// ---------------------------------------------------------------------------
// K1: argmin producer — VERBATIM the R7 kernel that ran clean (<54.7us,
// VGPR ~32, no spill). grid 1024 = (tile 0..511) x (code-half cg), 512
// threads (8 waves), launch_bounds(512,8) -> 64-reg cap honest here ->
// 8 waves/SIMD, 4 blocks/CU, 32 waves/CU (2x R8's latency hiding).
//   Swapped-operand MFMA mfma(emb, z): D[code][zrow]; argmin over codes
//   in-register + one shfl_xor(32) half-merge. In-place c_sq global loads
//   (NOT an LDS table: R9/R10 proved hoistable LDS values across the
//   unrolled MFMA bodies collapse the allocator -> 100MB+ scratch spill).
// Cross-block argmin: atomicMin into key_ws (64 distinct addrs/tile; low
// contention). cg==0 blocks also write zsq_g. Pair blocks (bid, bid+512)
// share a tile and an XCD (512%8==0) -> second z stage is L2-hit.
// argmin key = trunc(score*2^21)*1024 + code (monotone, first-min ties;
// identical math to R7/R8 -> bit-identical idx).
// ---------------------------------------------------------------------------
__global__ __launch_bounds__(512, 8)
void vq_argmin_kernel(const float* __restrict__ z, const f16* __restrict__ emb_h,
                      const float* __restrict__ c_sq, float* __restrict__ zsq_g,
                      int* __restrict__ key_ws) {
    __shared__ __align__(16) f16 z_s[32 * 64 * 8];   // [kg 32][row 64][8] = 32768 B
    __shared__ int   bl_key[8][64];                   // 2048 B
    __shared__ float zsq_part[8][64];                 // 2048 B

    const int tid = threadIdx.x;
    const int bid = blockIdx.x;
    const int tile = bid & 511;
    const int cg = bid >> 9;       // code-half: codes [cg*512, cg*512+512)
    const int n0 = tile * 64;
    const int b = n0 >> 10;
    const int hw0 = n0 & 1023;

    // ---- Phase A: stage z tile fp16 + per-row ||z||^2 partials ----
    {
        const int r = tid & 63;
        const int kq = tid >> 6;  // 0..7
        const float* zp = z + (size_t)b * (DD * 1024) + hw0 + r;
        float sq = 0.f;
        #pragma unroll
        for (int it = 0; it < 4; ++it) {
            int kg = kq * 4 + it;
            f16x8 hv;
            #pragma unroll
            for (int j = 0; j < 8; ++j) {
                float v = zp[(size_t)(kg * 8 + j) * 1024];
                sq += v * v;
                hv[j] = (f16)v;
            }
            *(f16x8*)&z_s[(kg * 64 + r) * 8] = hv;
        }
        zsq_part[kq][r] = sq;
    }
    __syncthreads();

    const int m = tid & 31;        // lane -> z row (D col)
    const int h = (tid >> 5) & 1;  // k-half; also selects code subset (+4h)
    const int w = tid >> 6;        // wave id 0..7

    int kmin0 = 0x7FFFFFFF;        // running key, z rows m
    int kmin1 = 0x7FFFFFFF;        // running key, z rows m+32

    // ---- Phase B: wave owns 64 codes as 2 chunks of 32 ----
    for (int c = 0; c < 2; ++c) {
        const int cb = cg * 512 + w * 64 + c * 32;     // chunk base code
        const f16* ebp = emb_h + (size_t)h * 8192 + (size_t)(cb + m) * 8;

        f32x16 acc0, acc1;   // D[code][row] for z rows 0-31 / 32-63
        #pragma unroll
        for (int i = 0; i < 16; ++i) { acc0[i] = 0.f; acc1[i] = 0.f; }

        #pragma unroll 2
        for (int ks = 0; ks < 16; ++ks) {
            const f16* za = z_s + ((size_t)(2 * ks + h) * 64 + m) * 8;
            f16x8 zb0 = *(const f16x8*)(za);           // z rows 0-31  (B frag)
            f16x8 zb1 = *(const f16x8*)(za + 256);     // z rows 32-63 (B frag)
            f16x8 ea  = *(const f16x8*)(ebp + (size_t)ks * 16384); // emb (A frag)
            acc0 = __builtin_amdgcn_mfma_f32_32x32x16_f16(ea, zb0, acc0, 0, 0, 0);
            acc1 = __builtin_amdgcn_mfma_f32_32x32x16_f16(ea, zb1, acc1, 0, 0, 0);
        }

        // in-register argmin over the 16 codes this lane holds
        #pragma unroll
        for (int reg = 0; reg < 16; ++reg) {
            int code = cb + (reg & 3) + 8 * (reg >> 2) + 4 * h;
            float cs = c_sq[code];
            float s0 = fmaf(-2.f, acc0[reg], cs);
            float s1 = fmaf(-2.f, acc1[reg], cs);
            kmin0 = min(kmin0, (int)(s0 * KEY_SCALE) * 1024 + code);
            kmin1 = min(kmin1, (int)(s1 * KEY_SCALE) * 1024 + code);
        }
    }

    // merge lane-halves (lanes m and m+32 hold the same z row, disjoint codes)
    kmin0 = min(kmin0, __shfl_xor(kmin0, 32));
    kmin1 = min(kmin1, __shfl_xor(kmin1, 32));
    if (h == 0) { bl_key[w][m] = kmin0; bl_key[w][32 + m] = kmin1; }
    __syncthreads();

    // ---- combine 8 waves -> device-scope atomicMin; cg0 writes zsq ----
    if (tid < 64) {
        int k = bl_key[0][tid];
        #pragma unroll
        for (int w2 = 1; w2 < 8; ++w2) k = min(k, bl_key[w2][tid]);
        atomicMin(&key_ws[n0 + tid], k);
        if (cg == 0) {
            float zq = 0.f;
            #pragma unroll
            for (int p = 0; p < 8; ++p) zq += zsq_part[p][tid];
            zsq_g[n0 + tid] = zq;
        }
    }
}

// ---------------------------------------------------------------------------
// K2: grid 1025, zero global atomics (R8's proven structure). Blocks
// 0..1023 = writers (tile x channel-half): idx = key_ws & 1023 (plain loads;
// kernel-boundary coherent), transposed LDS stage Qt[128][65], full 256B out
// lines. Block 1024 = finalize: histogram of key_ws codes (LDS atomics) ->
// entropy; loss = sum over rows of (key>>10)*KEY_INV + zsq_g.
// ---------------------------------------------------------------------------
__global__ __launch_bounds__(512, 4)
void vq_out_kernel(const float* __restrict__ emb, const int* __restrict__ key_ws,
                   const float* __restrict__ zsq_g, float* __restrict__ out,
                   float* __restrict__ out_tail) {
    __shared__ float Qt[128][65];   // 33280 B, transposed: [ch][row]
    __shared__ int   idx_s[64];

    const int tid = threadIdx.x;

    if (blockIdx.x == 1024) {
        // ---- finalize block ----
        __shared__ int   hist[KC];
        __shared__ float wsum[8];
        for (int k = tid; k < KC; k += 512) hist[k] = 0;
        __syncthreads();
        float lv = 0.f;
        for (int i = tid; i < NROWS; i += 512) {
            int k = key_ws[i];
            atomicAdd(&hist[k & 1023], 1);           // LDS atomic (cheap)
            lv += (float)(k >> 10) * KEY_INV + zsq_g[i];
        }
        __syncthreads();
        float s = 0.f;
        for (int k = tid; k < KC; k += 512) {
            float pr = (float)hist[k] * (1.0f / (float)NROWS);
            s += pr * logf(pr + 1e-10f);
        }
        #pragma unroll
        for (int off = 32; off > 0; off >>= 1) {
            s  += __shfl_down(s, off);
            lv += __shfl_down(lv, off);
        }
        if ((tid & 63) == 0) { wsum[tid >> 6] = s; Qt[0][tid >> 6] = lv; }
        __syncthreads();
        if (tid == 0) {
            float ent = 0.f, loss_tot = 0.f;
            #pragma unroll
            for (int p = 0; p < 8; ++p) { ent += wsum[p]; loss_tot += Qt[0][p]; }
            out_tail[0] = 1.25f * loss_tot * (1.0f / (float)NELEM);
            out_tail[1] = expf(-ent);
        }
        return;
    }

    const int tile = blockIdx.x >> 1;
    const int ch0 = (blockIdx.x & 1) * 128;
    const int n0 = tile * 64;
    const int b = n0 >> 10;
    const int hw0 = n0 & 1023;

    if (tid < 64) idx_s[tid] = key_ws[n0 + tid] & 1023;
    __syncthreads();

    // stage: thread (p=tid>>6, r=tid&63) loads emb[idx[r]][ch0+p*16..+16]
    // (coalesced 64B/lane from L2), scatters into Qt columns.
    {
        int r = tid & 63;
        int p = tid >> 6;
        const float* ep = emb + (size_t)idx_s[r] * DD + ch0 + p * 16;
        float4 v0 = *(const float4*)(ep);
        float4 v1 = *(const float4*)(ep + 4);
        float4 v2 = *(const float4*)(ep + 8);
        float4 v3 = *(const float4*)(ep + 12);
        float vv[16] = {v0.x, v0.y, v0.z, v0.w, v1.x, v1.y, v1.z, v1.w,
                        v2.x, v2.y, v2.z, v2.w, v3.x, v3.y, v3.z, v3.w};
        #pragma unroll
        for (int g = 0; g < 16; ++g)
            Qt[p * 16 + g][r] = vv[g];   // lanes r consecutive -> conflict-free
    }
    __syncthreads();

    // drain: wave w covers channels [w*16,(w+1)*16); per channel the 64 lanes
    // write one full 256B contiguous line of out. Then exit — no fence,
    // no atomic, no done counter.
    {
        int lane = tid & 63;
        int w = tid >> 6;
        const size_t base = (size_t)b * (DD * 1024) + hw0 + lane;
        #pragma unroll
        for (int g = 0; g < 16; ++g) {
            int ch = w * 16 + g;
            out[base + (size_t)(ch0 + ch) * 1024] = Qt[ch][lane];
        }
    }
}

// ---------------------------------------------------------------------------
extern "C" void kernel_launch(void* const* d_in, const int* in_sizes, int n_in,
                              void* d_out, int out_size, void* d_ws, size_t ws_size,
                              hipStream_t stream) {
    const float* z = (const float*)d_in[0];    // (32,256,32,32)
    const float* emb = (const float*)d_in[1];  // (1024,256)
    float* out = (float*)d_out;                // 8388608 + 2

    char* wsb = (char*)d_ws;
    f16* emb_h = (f16*)wsb;                        // 524288 B
    float* c_sq = (float*)(wsb + 524288);          // 4096 B
    int* key_ws = (int*)(wsb + 528384);            // 131072 B
    float* zsq_g = (float*)(wsb + 659456);         // 131072 B

    hipLaunchKernelGGL(vq_prep_kernel, dim3(256), dim3(256), 0, stream,
                       emb, emb_h, c_sq, key_ws);
    hipLaunchKernelGGL(vq_argmin_kernel, dim3(1024), dim3(512), 0, stream,
                       z, emb_h, c_sq, zsq_g, key_ws);
    hipLaunchKernelGGL(vq_out_kernel, dim3(1025), dim3(512), 0, stream,
                       emb, key_ws, zsq_g, out, out + NELEM);
}

// Round 12
// 121.129 us; speedup vs baseline: 3.3172x; 1.1881x over previous
//
#include <hip/hip_runtime.h>
#include <math.h>

// Problem constants
#define KC 1024       // num codes
#define DD 256        // embedding dim
#define NROWS 32768   // 32 * 32 * 32 (B*H*W)
#define NELEM 8388608 // NROWS * DD

typedef _Float16 f16;
typedef __attribute__((ext_vector_type(8))) _Float16 f16x8;
typedef __attribute__((ext_vector_type(16))) float f32x16;

#define KEY_SCALE 2097152.0f   // 2^21; |score| <= ~0.63 -> |ikey| < 2^21
#define KEY_INV   (1.0f / 2097152.0f)

// ---------------------------------------------------------------------------
// prep: c_sq (exact fp32) + emb -> fp16 swizzled + stat_done = 0.
// grid 256 x 256.  emb_h layout: [kg 32][code 1024][8]
// ---------------------------------------------------------------------------
__global__ void vq_prep_kernel(const float* __restrict__ emb, f16* __restrict__ emb_h,
                               float* __restrict__ c_sq, unsigned* __restrict__ stat_done) {
    const int tid = threadIdx.x;
    const int gt = blockIdx.x * 256 + tid;
    if (gt == 0) *stat_done = 0u;
    {
        int k = blockIdx.x * 4 + (tid >> 6);
        int lane = tid & 63;
        float4 v = *(const float4*)(emb + (size_t)k * DD + lane * 4);
        float s = v.x * v.x + v.y * v.y + v.z * v.z + v.w * v.w;
        #pragma unroll
        for (int off = 32; off > 0; off >>= 1) s += __shfl_down(s, off);
        if (lane == 0) c_sq[k] = s;
    }
    if (gt < 32768) {
        int code = gt & 1023;
        int kg = gt >> 10;
        const float* p = emb + (size_t)code * DD + kg * 8;
        float4 v0 = *(const float4*)p;
        float4 v1 = *(const float4*)(p + 4);
        f16x8 hcv;
        hcv[0] = (f16)v0.x; hcv[1] = (f16)v0.y; hcv[2] = (f16)v0.z; hcv[3] = (f16)v0.w;
        hcv[4] = (f16)v1.x; hcv[5] = (f16)v1.y; hcv[6] = (f16)v1.z; hcv[7] = (f16)v1.w;
        *(f16x8*)(emb_h + (size_t)gt * 8) = hcv;
    }
}

// ---------------------------------------------------------------------------
// K1: argmin producer — VERBATIM the R8 kernel (126.0us config; clean, no
// spill). grid 512, 512 threads (8 waves), 64 rows/block, ALL 1024 codes.
//   Swapped-operand MFMA mfma(emb, z): D[code][zrow] -> lane = z row,
//   reg = code; argmin over codes in-register + one shfl_xor(32) merge.
// SPILL LANDMINES (do not retry): R9's 2-deep manual load pipeline and
// R10's csq_s LDS table both gave the scheduler hoistable values across the
// unrolled MFMA bodies -> allocator pinned at 64 arch VGPRs -> 100MB+/
// dispatch scratch spill (83-375us). Keep c_sq loads IN-PLACE in the
// epilogue; keep #pragma unroll 2; no rotation registers.
// Outputs: idx_g (plain stores), loss_blk[bid] (plain store). Zero atomics.
// argmin key = trunc(score*2^21)*1024 + code (monotone, first-min ties).
// loss per row: sum_c (q-z)^2 = score_min + ||z||^2.
// ---------------------------------------------------------------------------
__global__ __launch_bounds__(512, 4)
void vq_argmin_kernel(const float* __restrict__ z, const f16* __restrict__ emb_h,
                      const float* __restrict__ c_sq, int* __restrict__ idx_g,
                      float* __restrict__ loss_blk) {
    __shared__ __align__(16) f16 z_s[32 * 64 * 8];   // [kg 32][row 64][8] = 32768 B
    __shared__ int   bl_key[8][64];                   // 2048 B
    __shared__ float zsq_part[8][64];                 // 2048 B

    const int tid = threadIdx.x;
    const int n0 = blockIdx.x * 64;
    const int b = n0 >> 10;
    const int hw0 = n0 & 1023;

    // ---- Phase A: stage z tile fp16 + per-row ||z||^2 partials ----
    {
        const int r = tid & 63;
        const int kq = tid >> 6;  // 0..7
        const float* zp = z + (size_t)b * (DD * 1024) + hw0 + r;
        float sq = 0.f;
        #pragma unroll
        for (int it = 0; it < 4; ++it) {
            int kg = kq * 4 + it;
            f16x8 hv;
            #pragma unroll
            for (int j = 0; j < 8; ++j) {
                float v = zp[(size_t)(kg * 8 + j) * 1024];
                sq += v * v;
                hv[j] = (f16)v;
            }
            *(f16x8*)&z_s[(kg * 64 + r) * 8] = hv;
        }
        zsq_part[kq][r] = sq;
    }
    __syncthreads();

    const int m = tid & 31;        // lane -> z row (D col)
    const int h = (tid >> 5) & 1;  // k-half; also selects code subset (+4h)
    const int w = tid >> 6;        // wave id 0..7

    int kmin0 = 0x7FFFFFFF;        // running key, z rows m
    int kmin1 = 0x7FFFFFFF;        // running key, z rows m+32

    // ---- Phase B: wave owns 128 codes as 4 chunks of 32 ----
    for (int c = 0; c < 4; ++c) {
        const int cb = w * 128 + c * 32;               // chunk base code
        const f16* ebp = emb_h + (size_t)h * 8192 + (size_t)(cb + m) * 8;

        f32x16 acc0, acc1;   // D[code][row] for z rows 0-31 / 32-63
        #pragma unroll
        for (int i = 0; i < 16; ++i) { acc0[i] = 0.f; acc1[i] = 0.f; }

        #pragma unroll 2
        for (int ks = 0; ks < 16; ++ks) {
            const f16* za = z_s + ((size_t)(2 * ks + h) * 64 + m) * 8;
            f16x8 zb0 = *(const f16x8*)(za);           // z rows 0-31  (B frag)
            f16x8 zb1 = *(const f16x8*)(za + 256);     // z rows 32-63 (B frag)
            f16x8 ea  = *(const f16x8*)(ebp + (size_t)ks * 16384); // emb (A frag)
            acc0 = __builtin_amdgcn_mfma_f32_32x32x16_f16(ea, zb0, acc0, 0, 0, 0);
            acc1 = __builtin_amdgcn_mfma_f32_32x32x16_f16(ea, zb1, acc1, 0, 0, 0);
        }

        // in-register argmin over the 16 codes this lane holds
        #pragma unroll
        for (int reg = 0; reg < 16; ++reg) {
            int code = cb + (reg & 3) + 8 * (reg >> 2) + 4 * h;
            float cs = c_sq[code];
            float s0 = fmaf(-2.f, acc0[reg], cs);
            float s1 = fmaf(-2.f, acc1[reg], cs);
            kmin0 = min(kmin0, (int)(s0 * KEY_SCALE) * 1024 + code);
            kmin1 = min(kmin1, (int)(s1 * KEY_SCALE) * 1024 + code);
        }
    }

    // merge lane-halves (lanes m and m+32 hold the same z row, disjoint codes)
    kmin0 = min(kmin0, __shfl_xor(kmin0, 32));
    kmin1 = min(kmin1, __shfl_xor(kmin1, 32));
    if (h == 0) { bl_key[w][m] = kmin0; bl_key[w][32 + m] = kmin1; }
    __syncthreads();

    // ---- combine 8 waves -> idx store + per-block loss (plain stores) ----
    if (tid < 64) {
        int k = bl_key[0][tid];
        #pragma unroll
        for (int w2 = 1; w2 < 8; ++w2) k = min(k, bl_key[w2][tid]);
        idx_g[n0 + tid] = k & 1023;     // low 10 bits = code
        float zq = 0.f;
        #pragma unroll
        for (int p = 0; p < 8; ++p) zq += zsq_part[p][tid];
        float lr = (float)(k >> 10) * KEY_INV + zq;  // score_min + ||z||^2
        #pragma unroll
        for (int off = 32; off > 0; off >>= 1) lr += __shfl_down(lr, off);
        if (tid == 0) loss_blk[blockIdx.x] = lr;     // NO atomic
    }
}

// ---------------------------------------------------------------------------
// K2: grid 1032. Blocks 0..1023 = writers (R8 verbatim: tile x channel-half,
// transposed LDS stage Qt[128][65], full 256B out lines, zero atomics).
// Blocks 1024..1031 = 8 PARALLEL stat blocks (replaces R8/R11's single
// finalize block whose ~30us solo tail dominated K2 — measured occupancy
// 9.5% on the K2 dispatch): block j LDS-histograms rows [j*4096,(j+1)*4096)
// of idx_g (8 coalesced iters) and plain-stores its 1024-bin partial to
// hist_g[j]. Last arriver (done-counter race, 8 increments, threadfence
// release/acquire + atomic reads — the R3-proven pattern) sums the 8
// partials -> entropy, sums loss_blk[512] (kernel-boundary plain loads)
// -> loss, writes out_tail.
// ---------------------------------------------------------------------------
__global__ __launch_bounds__(512, 4)
void vq_out_kernel(const float* __restrict__ emb, const int* __restrict__ idx_g,
                   const float* __restrict__ loss_blk, int* __restrict__ hist_g,
                   unsigned* __restrict__ stat_done, float* __restrict__ out,
                   float* __restrict__ out_tail) {
    __shared__ float Qt[128][65];   // 33280 B, transposed: [ch][row]
    __shared__ int   idx_s[64];
    __shared__ int   hist[KC];      // 4096 B (stat blocks)
    __shared__ float wsum[8];
    __shared__ int   flag_s;

    const int tid = threadIdx.x;
    const int bid = blockIdx.x;

    if (bid >= 1024) {
        // ---- stat block j: partial histogram of 4096 rows ----
        const int j = bid - 1024;
        for (int k = tid; k < KC; k += 512) hist[k] = 0;
        __syncthreads();
        #pragma unroll
        for (int it = 0; it < 8; ++it)
            atomicAdd(&hist[idx_g[j * 4096 + it * 512 + tid]], 1);  // LDS atomic
        __syncthreads();
        for (int k = tid; k < KC; k += 512) hist_g[j * KC + k] = hist[k];
        __threadfence();                 // release partial before signaling
        if (tid == 0) flag_s = (atomicAdd(stat_done, 1u) == 7u) ? 1 : 0;
        __syncthreads();
        if (!flag_s) return;
        __threadfence();                 // acquire others' partials

        // ---- last arriver: combine 8 partials -> entropy; loss_blk -> loss
        float s = 0.f;
        for (int k = tid; k < KC; k += 512) {
            int c = 0;
            #pragma unroll
            for (int p = 0; p < 8; ++p) c += atomicAdd(&hist_g[p * KC + k], 0);
            float pr = (float)c * (1.0f / (float)NROWS);
            s += pr * logf(pr + 1e-10f);
        }
        float lv = loss_blk[tid];        // 512 partials from K1 (prev kernel)
        #pragma unroll
        for (int off = 32; off > 0; off >>= 1) {
            s  += __shfl_down(s, off);
            lv += __shfl_down(lv, off);
        }
        if ((tid & 63) == 0) { wsum[tid >> 6] = s; Qt[0][tid >> 6] = lv; }
        __syncthreads();
        if (tid == 0) {
            float ent = 0.f, loss_tot = 0.f;
            #pragma unroll
            for (int p = 0; p < 8; ++p) { ent += wsum[p]; loss_tot += Qt[0][p]; }
            out_tail[0] = 1.25f * loss_tot * (1.0f / (float)NELEM);
            out_tail[1] = expf(-ent);
        }
        return;
    }

    const int tile = bid >> 1;
    const int ch0 = (bid & 1) * 128;
    const int n0 = tile * 64;
    const int b = n0 >> 10;
    const int hw0 = n0 & 1023;

    if (tid < 64) idx_s[tid] = idx_g[n0 + tid];
    __syncthreads();

    // stage: thread (p=tid>>6, r=tid&63) loads emb[idx[r]][ch0+p*16..+16]
    // (coalesced 64B/lane from L2), scatters into Qt columns.
    {
        int r = tid & 63;
        int p = tid >> 6;
        const float* ep = emb + (size_t)idx_s[r] * DD + ch0 + p * 16;
        float4 v0 = *(const float4*)(ep);
        float4 v1 = *(const float4*)(ep + 4);
        float4 v2 = *(const float4*)(ep + 8);
        float4 v3 = *(const float4*)(ep + 12);
        float vv[16] = {v0.x, v0.y, v0.z, v0.w, v1.x, v1.y, v1.z, v1.w,
                        v2.x, v2.y, v2.z, v2.w, v3.x, v3.y, v3.z, v3.w};
        #pragma unroll
        for (int g = 0; g < 16; ++g)
            Qt[p * 16 + g][r] = vv[g];   // lanes r consecutive -> conflict-free
    }
    __syncthreads();

    // drain: wave w covers channels [w*16,(w+1)*16); per channel the 64 lanes
    // write one full 256B contiguous line of out. Then exit — no fence,
    // no atomic, no done counter.
    {
        int lane = tid & 63;
        int w = tid >> 6;
        const size_t base = (size_t)b * (DD * 1024) + hw0 + lane;
        #pragma unroll
        for (int g = 0; g < 16; ++g) {
            int ch = w * 16 + g;
            out[base + (size_t)(ch0 + ch) * 1024] = Qt[ch][lane];
        }
    }
}

// ---------------------------------------------------------------------------
extern "C" void kernel_launch(void* const* d_in, const int* in_sizes, int n_in,
                              void* d_out, int out_size, void* d_ws, size_t ws_size,
                              hipStream_t stream) {
    const float* z = (const float*)d_in[0];    // (32,256,32,32)
    const float* emb = (const float*)d_in[1];  // (1024,256)
    float* out = (float*)d_out;                // 8388608 + 2

    char* wsb = (char*)d_ws;
    f16* emb_h = (f16*)wsb;                        // 524288 B
    float* c_sq = (float*)(wsb + 524288);          // 4096 B
    int* idx_g = (int*)(wsb + 528384);             // 131072 B
    float* loss_blk = (float*)(wsb + 659456);      // 2048 B
    int* hist_g = (int*)(wsb + 661504);            // 32768 B
    unsigned* stat_done = (unsigned*)(wsb + 694272); // 4 B

    hipLaunchKernelGGL(vq_prep_kernel, dim3(256), dim3(256), 0, stream,
                       emb, emb_h, c_sq, stat_done);
    hipLaunchKernelGGL(vq_argmin_kernel, dim3(512), dim3(512), 0, stream,
                       z, emb_h, c_sq, idx_g, loss_blk);
    hipLaunchKernelGGL(vq_out_kernel, dim3(1032), dim3(512), 0, stream,
                       emb, idx_g, loss_blk, hist_g, stat_done, out, out + NELEM);
}

// Round 13
// 117.890 us; speedup vs baseline: 3.4083x; 1.0275x over previous
//
#include <hip/hip_runtime.h>
#include <math.h>

// Problem constants
#define KC 1024       // num codes
#define DD 256        // embedding dim
#define NROWS 32768   // 32 * 32 * 32 (B*H*W)
#define NELEM 8388608 // NROWS * DD

typedef _Float16 f16;
typedef __attribute__((ext_vector_type(8))) _Float16 f16x8;
typedef __attribute__((ext_vector_type(16))) float f32x16;

#define KEY_SCALE 2097152.0f   // 2^21; |score| <= ~0.63 -> |ikey| < 2^21
#define KEY_INV   (1.0f / 2097152.0f)

// ---------------------------------------------------------------------------
// prep: c_sq (exact fp32) + emb -> fp16 swizzled + stat_done = 0.
// grid 256 x 256.  emb_h layout: [kg 32][code 1024][8]
// ---------------------------------------------------------------------------
__global__ void vq_prep_kernel(const float* __restrict__ emb, f16* __restrict__ emb_h,
                               float* __restrict__ c_sq, unsigned* __restrict__ stat_done) {
    const int tid = threadIdx.x;
    const int gt = blockIdx.x * 256 + tid;
    if (gt == 0) *stat_done = 0u;
    {
        int k = blockIdx.x * 4 + (tid >> 6);
        int lane = tid & 63;
        float4 v = *(const float4*)(emb + (size_t)k * DD + lane * 4);
        float s = v.x * v.x + v.y * v.y + v.z * v.z + v.w * v.w;
        #pragma unroll
        for (int off = 32; off > 0; off >>= 1) s += __shfl_down(s, off);
        if (lane == 0) c_sq[k] = s;
    }
    if (gt < 32768) {
        int code = gt & 1023;
        int kg = gt >> 10;
        const float* p = emb + (size_t)code * DD + kg * 8;
        float4 v0 = *(const float4*)p;
        float4 v1 = *(const float4*)(p + 4);
        f16x8 hcv;
        hcv[0] = (f16)v0.x; hcv[1] = (f16)v0.y; hcv[2] = (f16)v0.z; hcv[3] = (f16)v0.w;
        hcv[4] = (f16)v1.x; hcv[5] = (f16)v1.y; hcv[6] = (f16)v1.z; hcv[7] = (f16)v1.w;
        *(f16x8*)(emb_h + (size_t)gt * 8) = hcv;
    }
}

// ---------------------------------------------------------------------------
// K1: argmin producer, swapped-operand MFMA, 128-ROW TILES (R12 change):
// grid 256, 512 threads (8 waves), 128 rows/block, ALL 1024 codes/block.
// Wave w owns codes [w*128,(w+1)*128) (identical to R8) but now computes
// FOUR 32-row groups per chunk: each ea L2 load feeds 4 MFMAs (2x the
// latency cover of R8's 2) and aggregate emb_h L2 draw halves to 128MB.
// LDS 72KB -> 2 blocks/CU, 16 waves/CU (same as R8).
//   mfma(emb, z): D[code][zrow] -> lane = z row, reg = code; argmin over
//   codes in-register + one shfl_xor(32) half-merge.
// SPILL LANDMINES (do not retry): R9's manual 2-deep load pipeline and
// R10's csq_s LDS table both gave the scheduler hoistable values across
// the unrolled MFMA bodies -> allocator collapse -> 100MB+/dispatch
// scratch. Keep c_sq loads IN-PLACE in the epilogue; #pragma unroll 2;
// no rotation registers. Budget here: 64 acc + ~45 arch ~= 110 < 128 cap.
// Outputs: idx_g (plain stores), loss_blk[bid] (plain store). Zero atomics.
// argmin key = trunc(score*2^21)*1024 + code (monotone, first-min ties;
// same per-wave code ranges and math as R8 -> bitwise-identical keys).
// ---------------------------------------------------------------------------
__global__ __launch_bounds__(512, 4)
void vq_argmin_kernel(const float* __restrict__ z, const f16* __restrict__ emb_h,
                      const float* __restrict__ c_sq, int* __restrict__ idx_g,
                      float* __restrict__ loss_blk) {
    __shared__ __align__(16) f16 z_s[32 * 128 * 8];  // [kg 32][row 128][8] = 65536 B
    __shared__ int   bl_key[8][128];                  // 4096 B
    __shared__ float zsq_part[8][128];                // 4096 B
    __shared__ float lsum2[2];

    const int tid = threadIdx.x;
    const int n0 = blockIdx.x * 128;   // 128-row tile; never straddles an image
    const int b = n0 >> 10;
    const int hw0 = n0 & 1023;

    // ---- Phase A: stage 128-row z tile fp16 + per-row ||z||^2 partials ----
    {
        const int r2 = tid & 63;
        const int kq = tid >> 6;  // 0..7
        #pragma unroll
        for (int rh = 0; rh < 2; ++rh) {
            const int r = rh * 64 + r2;
            const float* zp = z + (size_t)b * (DD * 1024) + hw0 + r;
            float sq = 0.f;
            #pragma unroll
            for (int it = 0; it < 4; ++it) {
                int kg = kq * 4 + it;
                f16x8 hv;
                #pragma unroll
                for (int j = 0; j < 8; ++j) {
                    float v = zp[(size_t)(kg * 8 + j) * 1024];
                    sq += v * v;
                    hv[j] = (f16)v;
                }
                *(f16x8*)&z_s[(kg * 128 + r) * 8] = hv;
            }
            zsq_part[kq][r] = sq;
        }
    }
    __syncthreads();

    const int m = tid & 31;        // lane -> z row within each 32-row group
    const int h = (tid >> 5) & 1;  // k-half; also selects code subset (+4h)
    const int w = tid >> 6;        // wave id 0..7

    int kmin0 = 0x7FFFFFFF;        // rows m
    int kmin1 = 0x7FFFFFFF;        // rows m+32
    int kmin2 = 0x7FFFFFFF;        // rows m+64
    int kmin3 = 0x7FFFFFFF;        // rows m+96

    // ---- Phase B: wave owns 128 codes as 4 chunks of 32; 4 row-groups ----
    for (int c = 0; c < 4; ++c) {
        const int cb = w * 128 + c * 32;               // chunk base code
        const f16* ebp = emb_h + (size_t)h * 8192 + (size_t)(cb + m) * 8;

        f32x16 acc0, acc1, acc2, acc3;  // D[code][row] per 32-row group
        #pragma unroll
        for (int i = 0; i < 16; ++i) {
            acc0[i] = 0.f; acc1[i] = 0.f; acc2[i] = 0.f; acc3[i] = 0.f;
        }

        #pragma unroll 2
        for (int ks = 0; ks < 16; ++ks) {
            const f16* za = z_s + ((size_t)(2 * ks + h) * 128 + m) * 8;
            f16x8 zb0 = *(const f16x8*)(za);           // rows 0-31
            f16x8 zb1 = *(const f16x8*)(za + 256);     // rows 32-63
            f16x8 zb2 = *(const f16x8*)(za + 512);     // rows 64-95
            f16x8 zb3 = *(const f16x8*)(za + 768);     // rows 96-127
            f16x8 ea  = *(const f16x8*)(ebp + (size_t)ks * 16384); // emb (A frag)
            acc0 = __builtin_amdgcn_mfma_f32_32x32x16_f16(ea, zb0, acc0, 0, 0, 0);
            acc1 = __builtin_amdgcn_mfma_f32_32x32x16_f16(ea, zb1, acc1, 0, 0, 0);
            acc2 = __builtin_amdgcn_mfma_f32_32x32x16_f16(ea, zb2, acc2, 0, 0, 0);
            acc3 = __builtin_amdgcn_mfma_f32_32x32x16_f16(ea, zb3, acc3, 0, 0, 0);
        }

        // in-register argmin over the 16 codes this lane holds (c_sq in-place)
        #pragma unroll
        for (int reg = 0; reg < 16; ++reg) {
            int code = cb + (reg & 3) + 8 * (reg >> 2) + 4 * h;
            float cs = c_sq[code];
            float s0 = fmaf(-2.f, acc0[reg], cs);
            float s1 = fmaf(-2.f, acc1[reg], cs);
            float s2 = fmaf(-2.f, acc2[reg], cs);
            float s3 = fmaf(-2.f, acc3[reg], cs);
            kmin0 = min(kmin0, (int)(s0 * KEY_SCALE) * 1024 + code);
            kmin1 = min(kmin1, (int)(s1 * KEY_SCALE) * 1024 + code);
            kmin2 = min(kmin2, (int)(s2 * KEY_SCALE) * 1024 + code);
            kmin3 = min(kmin3, (int)(s3 * KEY_SCALE) * 1024 + code);
        }
    }

    // merge lane-halves (lanes m and m+32 hold the same z row, disjoint codes)
    kmin0 = min(kmin0, __shfl_xor(kmin0, 32));
    kmin1 = min(kmin1, __shfl_xor(kmin1, 32));
    kmin2 = min(kmin2, __shfl_xor(kmin2, 32));
    kmin3 = min(kmin3, __shfl_xor(kmin3, 32));
    if (h == 0) {
        bl_key[w][m]      = kmin0;
        bl_key[w][32 + m] = kmin1;
        bl_key[w][64 + m] = kmin2;
        bl_key[w][96 + m] = kmin3;
    }
    __syncthreads();

    // ---- combine 8 waves -> idx store + per-block loss (plain stores) ----
    if (tid < 128) {
        int k = bl_key[0][tid];
        #pragma unroll
        for (int w2 = 1; w2 < 8; ++w2) k = min(k, bl_key[w2][tid]);
        idx_g[n0 + tid] = k & 1023;     // low 10 bits = code
        float zq = 0.f;
        #pragma unroll
        for (int p = 0; p < 8; ++p) zq += zsq_part[p][tid];
        float lr = (float)(k >> 10) * KEY_INV + zq;  // score_min + ||z||^2
        #pragma unroll
        for (int off = 32; off > 0; off >>= 1) lr += __shfl_down(lr, off);
        if ((tid & 63) == 0) lsum2[tid >> 6] = lr;
    }
    __syncthreads();
    if (tid == 0) loss_blk[blockIdx.x] = lsum2[0] + lsum2[1];   // NO atomic
}

// ---------------------------------------------------------------------------
// K2: grid 1032. Blocks 0..1023 = writers (tile x channel-half, transposed
// LDS stage Qt[128][65], full 256B out lines, zero atomics). Blocks
// 1024..1031 = 8 parallel stat blocks; last arriver (done-counter race,
// threadfence release/acquire + atomic reads) combines partial histograms
// -> entropy, sums loss_blk[256] -> loss, writes out_tail.
// ---------------------------------------------------------------------------
__global__ __launch_bounds__(512, 4)
void vq_out_kernel(const float* __restrict__ emb, const int* __restrict__ idx_g,
                   const float* __restrict__ loss_blk, int* __restrict__ hist_g,
                   unsigned* __restrict__ stat_done, float* __restrict__ out,
                   float* __restrict__ out_tail) {
    __shared__ float Qt[128][65];   // 33280 B, transposed: [ch][row]
    __shared__ int   idx_s[64];
    __shared__ int   hist[KC];      // 4096 B (stat blocks)
    __shared__ float wsum[8];
    __shared__ int   flag_s;

    const int tid = threadIdx.x;
    const int bid = blockIdx.x;

    if (bid >= 1024) {
        // ---- stat block j: partial histogram of 4096 rows ----
        const int j = bid - 1024;
        for (int k = tid; k < KC; k += 512) hist[k] = 0;
        __syncthreads();
        #pragma unroll
        for (int it = 0; it < 8; ++it)
            atomicAdd(&hist[idx_g[j * 4096 + it * 512 + tid]], 1);  // LDS atomic
        __syncthreads();
        for (int k = tid; k < KC; k += 512) hist_g[j * KC + k] = hist[k];
        __threadfence();                 // release partial before signaling
        if (tid == 0) flag_s = (atomicAdd(stat_done, 1u) == 7u) ? 1 : 0;
        __syncthreads();
        if (!flag_s) return;
        __threadfence();                 // acquire others' partials

        // ---- last arriver: combine 8 partials -> entropy; loss_blk -> loss
        float s = 0.f;
        for (int k = tid; k < KC; k += 512) {
            int c = 0;
            #pragma unroll
            for (int p = 0; p < 8; ++p) c += atomicAdd(&hist_g[p * KC + k], 0);
            float pr = (float)c * (1.0f / (float)NROWS);
            s += pr * logf(pr + 1e-10f);
        }
        float lv = (tid < 256) ? loss_blk[tid] : 0.f;  // 256 partials from K1
        #pragma unroll
        for (int off = 32; off > 0; off >>= 1) {
            s  += __shfl_down(s, off);
            lv += __shfl_down(lv, off);
        }
        if ((tid & 63) == 0) { wsum[tid >> 6] = s; Qt[0][tid >> 6] = lv; }
        __syncthreads();
        if (tid == 0) {
            float ent = 0.f, loss_tot = 0.f;
            #pragma unroll
            for (int p = 0; p < 8; ++p) { ent += wsum[p]; loss_tot += Qt[0][p]; }
            out_tail[0] = 1.25f * loss_tot * (1.0f / (float)NELEM);
            out_tail[1] = expf(-ent);
        }
        return;
    }

    const int tile = bid >> 1;
    const int ch0 = (bid & 1) * 128;
    const int n0 = tile * 64;
    const int b = n0 >> 10;
    const int hw0 = n0 & 1023;

    if (tid < 64) idx_s[tid] = idx_g[n0 + tid];
    __syncthreads();

    // stage: thread (p=tid>>6, r=tid&63) loads emb[idx[r]][ch0+p*16..+16]
    // (coalesced 64B/lane from L2), scatters into Qt columns.
    {
        int r = tid & 63;
        int p = tid >> 6;
        const float* ep = emb + (size_t)idx_s[r] * DD + ch0 + p * 16;
        float4 v0 = *(const float4*)(ep);
        float4 v1 = *(const float4*)(ep + 4);
        float4 v2 = *(const float4*)(ep + 8);
        float4 v3 = *(const float4*)(ep + 12);
        float vv[16] = {v0.x, v0.y, v0.z, v0.w, v1.x, v1.y, v1.z, v1.w,
                        v2.x, v2.y, v2.z, v2.w, v3.x, v3.y, v3.z, v3.w};
        #pragma unroll
        for (int g = 0; g < 16; ++g)
            Qt[p * 16 + g][r] = vv[g];   // lanes r consecutive -> conflict-free
    }
    __syncthreads();

    // drain: wave w covers channels [w*16,(w+1)*16); per channel the 64 lanes
    // write one full 256B contiguous line of out. Then exit — no fence,
    // no atomic, no done counter.
    {
        int lane = tid & 63;
        int w = tid >> 6;
        const size_t base = (size_t)b * (DD * 1024) + hw0 + lane;
        #pragma unroll
        for (int g = 0; g < 16; ++g) {
            int ch = w * 16 + g;
            out[base + (size_t)(ch0 + ch) * 1024] = Qt[ch][lane];
        }
    }
}

// ---------------------------------------------------------------------------
extern "C" void kernel_launch(void* const* d_in, const int* in_sizes, int n_in,
                              void* d_out, int out_size, void* d_ws, size_t ws_size,
                              hipStream_t stream) {
    const float* z = (const float*)d_in[0];    // (32,256,32,32)
    const float* emb = (const float*)d_in[1];  // (1024,256)
    float* out = (float*)d_out;                // 8388608 + 2

    char* wsb = (char*)d_ws;
    f16* emb_h = (f16*)wsb;                        // 524288 B
    float* c_sq = (float*)(wsb + 524288);          // 4096 B
    int* idx_g = (int*)(wsb + 528384);             // 131072 B
    float* loss_blk = (float*)(wsb + 659456);      // 1024 B (256 blocks)
    int* hist_g = (int*)(wsb + 661504);            // 32768 B
    unsigned* stat_done = (unsigned*)(wsb + 694272); // 4 B

    hipLaunchKernelGGL(vq_prep_kernel, dim3(256), dim3(256), 0, stream,
                       emb, emb_h, c_sq, stat_done);
    hipLaunchKernelGGL(vq_argmin_kernel, dim3(256), dim3(512), 0, stream,
                       z, emb_h, c_sq, idx_g, loss_blk);
    hipLaunchKernelGGL(vq_out_kernel, dim3(1032), dim3(512), 0, stream,
                       emb, idx_g, loss_blk, hist_g, stat_done, out, out + NELEM);
}